// Round 13
// baseline (149.864 us; speedup 1.0000x reference)
//
#include <hip/hip_runtime.h>
#include <hip/hip_bf16.h>
#include <math.h>

#define N_SPECIES 4
#define NNZ       16384
#define MPS       4096      // NNZ / N_SPECIES
#define N_CELLS   512
#define N_LATENT  256
#define HDIM      1024
#define N_GENES   20000

#define STRIPE    128                       // genes per bucket stripe
#define NSTRIPE   157                       // ceil(20000/128)
#define NBUCKET   (N_SPECIES * NSTRIPE)     // 628
#define CAP       128
#define KCHUNK    32                        // k-rows per staged chunk
#define KSLICE    64                        // k-rows per decode block
#define NSLICE    (HDIM / KSLICE)           // 16

typedef __bf16 bf16x8 __attribute__((ext_vector_type(8)));
typedef float  f32x4  __attribute__((ext_vector_type(4)));

static __device__ __forceinline__ unsigned short f2b(float f) {
    __hip_bfloat16 h = __float2bfloat16(f);
    return __builtin_bit_cast(unsigned short, h);
}
static __device__ __forceinline__ float b2f(unsigned short u) {
    return __builtin_bit_cast(float, (unsigned int)u << 16);
}
static __device__ __forceinline__ float softplusf(float x) {
    return (x > 20.f) ? x : log1pf(expf(x));
}

// ---------------------------------------------------------------------------
// Kernel 1: weight transposes + FUSED single-block bucketing.
//  y in [0,48): W1/W2 transpose tiles (R12 path, unchanged).
//  y == 48, x==0, z==0: ONE block buckets all 16384 entries with LDS counters
//  (zero -> barrier -> LDS-atomic bucket -> flush counts). Intra-block
//  __syncthreads gives the zero->bucket ordering that previously required two
//  kernel launches. Entry-list order from atomics is output-irrelevant.
// ---------------------------------------------------------------------------
__global__ __launch_bounds__(256) void transpose_and_bucket(
    const float* __restrict__ W1, const float* __restrict__ W2,
    unsigned short* __restrict__ Wt1, unsigned short* __restrict__ Wt2,
    const int* __restrict__ bidx, const int* __restrict__ gidx,
    int* __restrict__ counts, int4* __restrict__ lists4, int* __restrict__ ovf_list)
{
    __shared__ float tile[32][33];
    __shared__ int   lcnt[NBUCKET + 1];
    int s = blockIdx.z, y = blockIdx.y;
    int tx = threadIdx.x, ty = threadIdx.y;   // block (32, 8)
    int tid = ty * 32 + tx;

    if (y == 48) {
        if (blockIdx.x != 0 || blockIdx.z != 0) return;
        for (int i = tid; i <= NBUCKET; i += 256) lcnt[i] = 0;
        __syncthreads();
        for (int j = tid; j < NNZ; j += 256) {
            int g  = gidx[j];
            int sb = (j >> 12) * NSTRIPE + (g >> 7);
            int pos = atomicAdd(&lcnt[sb], 1);
            if (pos < CAP) lists4[sb * CAP + pos] = make_int4(j, bidx[j], g, 0);
            else           ovf_list[atomicAdd(&lcnt[NBUCKET], 1)] = j;
        }
        __syncthreads();
        for (int i = tid; i <= NBUCKET; i += 256) counts[i] = lcnt[i];
        return;
    }

    const float* Ws; unsigned short* Wts; int K, k0;
    if (y < 16) { Ws = W1 + (size_t)s * 512 * HDIM;  Wts = Wt1 + (size_t)s * HDIM * 512;  K = 512;  k0 = y * 32; }
    else        { Ws = W2 + (size_t)s * HDIM * HDIM; Wts = Wt2 + (size_t)s * HDIM * HDIM; K = HDIM; k0 = (y - 16) * 32; }
    int n0 = blockIdx.x * 32;
    #pragma unroll
    for (int p = 0; p < 4; p++)
        tile[ty + 8 * p][tx] = Ws[(size_t)(k0 + ty + 8 * p) * HDIM + n0 + tx];
    __syncthreads();
    #pragma unroll
    for (int p = 0; p < 4; p++) {
        int r = ty + 8 * p;
        Wts[(size_t)(n0 + r) * K + k0 + tx] = f2b(tile[tx][r]);
    }
}

// ---------------------------------------------------------------------------
// Kernel 2: GEMM layer 1 with FUSED input build (R10/R12 version, Wt1 bf16).
// ---------------------------------------------------------------------------
__global__ __launch_bounds__(256) void gemm1_fused(
    const float* __restrict__ z, const float* __restrict__ gl,
    const int* __restrict__ bidx, const unsigned short* __restrict__ Bt,
    const float* __restrict__ bias, unsigned short* __restrict__ C)
{
    int s = blockIdx.z;
    const unsigned short* Bs = Bt + (size_t)s * HDIM * 512;
    const float* bvec = bias + (size_t)s * HDIM;
    int m0 = blockIdx.x * 64, n0 = blockIdx.y * 64;

    __shared__ unsigned short Alds[64 * 64];
    __shared__ unsigned short Blds[64 * 64];

    int tid = threadIdx.x, lane = tid & 63, w = tid >> 6;
    int wr = w >> 1, wc = w & 1;
    f32x4 acc[2][2] = {};

    for (int kt = 0; kt < 512; kt += 64) {
        #pragma unroll
        for (int it = 0; it < 2; it++) {
            int c = it * 256 + tid;
            int row = c >> 3, kb = c & 7;
            int pa = kb ^ (row & 7);
            int col = kt + kb * 8;
            const float* src;
            if (col < N_LATENT)
                src = z + ((size_t)s * MPS + m0 + row) * N_LATENT + col;
            else
                src = gl + (size_t)bidx[s * MPS + m0 + row] * N_LATENT + (col - N_LATENT);
            float4 f0 = *(const float4*)src;
            float4 f1 = *(const float4*)(src + 4);
            unsigned short o[8] = { f2b(f0.x), f2b(f0.y), f2b(f0.z), f2b(f0.w),
                                    f2b(f1.x), f2b(f1.y), f2b(f1.z), f2b(f1.w) };
            *(uint4*)(Alds + row * 64 + pa * 8) = *(const uint4*)o;
            uint4 vb = *(const uint4*)(Bs + (size_t)(n0 + row) * 512 + kt + kb * 8);
            *(uint4*)(Blds + row * 64 + pa * 8) = vb;
        }
        __syncthreads();
        #pragma unroll
        for (int ks = 0; ks < 2; ks++) {
            bf16x8 af[2], bfr[2];
            #pragma unroll
            for (int f = 0; f < 2; f++) {
                int ar  = wr * 32 + f * 16 + (lane & 15);
                int akb = (ks * 4 + (lane >> 4)) ^ (ar & 7);
                af[f]  = __builtin_bit_cast(bf16x8, *(const uint4*)(Alds + ar * 64 + akb * 8));
                int br  = wc * 32 + f * 16 + (lane & 15);
                int bkb = (ks * 4 + (lane >> 4)) ^ (br & 7);
                bfr[f] = __builtin_bit_cast(bf16x8, *(const uint4*)(Blds + br * 64 + bkb * 8));
            }
            #pragma unroll
            for (int fm = 0; fm < 2; fm++)
                #pragma unroll
                for (int fn = 0; fn < 2; fn++)
                    acc[fm][fn] = __builtin_amdgcn_mfma_f32_16x16x32_bf16(
                        af[fm], bfr[fn], acc[fm][fn], 0, 0, 0);
        }
        __syncthreads();
    }

    #pragma unroll
    for (int fm = 0; fm < 2; fm++)
        #pragma unroll
        for (int fn = 0; fn < 2; fn++) {
            int col = n0 + wc * 32 + fn * 16 + (lane & 15);
            float bv = bvec[col];
            #pragma unroll
            for (int r = 0; r < 4; r++) {
                int row = m0 + wr * 32 + fm * 16 + (lane >> 4) * 4 + r;
                float v = fmaxf(acc[fm][fn][r] + bv, 0.0f);
                C[(size_t)s * N_CELLS * HDIM + (size_t)row * HDIM + col] = f2b(v);
            }
        }
}

// ---------------------------------------------------------------------------
// Kernel 3: generic bf16 MFMA GEMM (layer 2, Wt2 bf16)
// ---------------------------------------------------------------------------
__global__ __launch_bounds__(256) void gemm_bf16_mfma(
    const unsigned short* __restrict__ A, const unsigned short* __restrict__ Bt,
    const float* __restrict__ bias, unsigned short* __restrict__ C,
    int M, int N, int K)
{
    int s = blockIdx.z;
    const unsigned short* As = A  + (size_t)s * M * K;
    const unsigned short* Bs = Bt + (size_t)s * N * K;
    const float* bvec = bias + (size_t)s * N;
    int m0 = blockIdx.x * 64, n0 = blockIdx.y * 64;

    __shared__ unsigned short Alds[64 * 64];
    __shared__ unsigned short Blds[64 * 64];

    int tid = threadIdx.x, lane = tid & 63, w = tid >> 6;
    int wr = w >> 1, wc = w & 1;
    f32x4 acc[2][2] = {};

    for (int kt = 0; kt < K; kt += 64) {
        #pragma unroll
        for (int it = 0; it < 2; it++) {
            int c = it * 256 + tid;
            int row = c >> 3, kb = c & 7;
            int pa = kb ^ (row & 7);
            uint4 va = *(const uint4*)(As + (size_t)(m0 + row) * K + kt + kb * 8);
            *(uint4*)(Alds + row * 64 + pa * 8) = va;
            uint4 vb = *(const uint4*)(Bs + (size_t)(n0 + row) * K + kt + kb * 8);
            *(uint4*)(Blds + row * 64 + pa * 8) = vb;
        }
        __syncthreads();
        #pragma unroll
        for (int ks = 0; ks < 2; ks++) {
            bf16x8 af[2], bfr[2];
            #pragma unroll
            for (int f = 0; f < 2; f++) {
                int ar  = wr * 32 + f * 16 + (lane & 15);
                int akb = (ks * 4 + (lane >> 4)) ^ (ar & 7);
                af[f]  = __builtin_bit_cast(bf16x8, *(const uint4*)(Alds + ar * 64 + akb * 8));
                int br  = wc * 32 + f * 16 + (lane & 15);
                int bkb = (ks * 4 + (lane >> 4)) ^ (br & 7);
                bfr[f] = __builtin_bit_cast(bf16x8, *(const uint4*)(Blds + br * 64 + bkb * 8));
            }
            #pragma unroll
            for (int fm = 0; fm < 2; fm++)
                #pragma unroll
                for (int fn = 0; fn < 2; fn++)
                    acc[fm][fn] = __builtin_amdgcn_mfma_f32_16x16x32_bf16(
                        af[fm], bfr[fn], acc[fm][fn], 0, 0, 0);
        }
        __syncthreads();
    }

    #pragma unroll
    for (int fm = 0; fm < 2; fm++)
        #pragma unroll
        for (int fn = 0; fn < 2; fn++) {
            int col = n0 + wc * 32 + fn * 16 + (lane & 15);
            float bv = bvec[col];
            #pragma unroll
            for (int r = 0; r < 4; r++) {
                int row = m0 + wr * 32 + fm * 16 + (lane >> 4) * 4 + r;
                float v = fmaxf(acc[fm][fn][r] + bv, 0.0f);
                C[(size_t)s * M * N + (size_t)row * N + col] = f2b(v);
            }
        }
}

// ---------------------------------------------------------------------------
// Kernel 4: k-sliced stripe decode, latency-ordered (R10/R12 structure).
// ---------------------------------------------------------------------------
__global__ __launch_bounds__(256) void decode_slice(
    const unsigned short* __restrict__ H2b, const int* __restrict__ bidx,
    const int* __restrict__ gidx, const float* __restrict__ W3,
    const int* __restrict__ counts, const int4* __restrict__ lists4,
    const int* __restrict__ ovf_list, float* __restrict__ partial)
{
    __shared__ float tile[STRIPE][KCHUNK + 1];   // [gene][k] transposed
    int sb = blockIdx.x, sl = blockIdx.y;
    int s  = sb / NSTRIPE;
    int g0 = (sb % NSTRIPE) * STRIPE;
    int tid = threadIdx.x, lane = tid & 63, w = tid >> 6;
    int hw = lane >> 5, l32 = lane & 31;
    int k0 = sl * KSLICE;
    const float* Ws = W3 + (size_t)s * HDIM * N_GENES;

    // ---- 1) ISSUE FIRST: 8x W3 float4 (both chunks)
    int rb = tid >> 5;                 // 0..7 (k-row sub-index)
    int gq = tid & 31;                 // gene quad within stripe
    int gcl = g0 + gq * 4;
    gcl = (gcl <= N_GENES - 4) ? gcl : (N_GENES - 4);   // tail clamp
    float4 q[8];
    #pragma unroll
    for (int c = 0; c < 2; c++)
        #pragma unroll
        for (int p = 0; p < 4; p++)
            q[c * 4 + p] = *(const float4*)(
                Ws + (size_t)(k0 + c * 32 + p * 8 + rb) * N_GENES + gcl);

    // ---- 2) metadata overlapped with W3 flight (speculative, clamped-safe)
    int cnt = counts[sb];
    int jj[8], gg[8];
    float hv[8][2];
    {
        int4 L[8];
        #pragma unroll
        for (int e = 0; e < 8; e++)
            L[e] = lists4[sb * CAP + (e * 8 + w * 2 + hw)];
        #pragma unroll
        for (int e = 0; e < 8; e++) {
            const unsigned short* hp =
                H2b + ((size_t)s * N_CELLS + (L[e].y & (N_CELLS - 1))) * HDIM + k0;
            hv[e][0] = b2f(hp[l32]);
            hv[e][1] = b2f(hp[32 + l32]);
            jj[e] = L[e].x;
            gg[e] = L[e].z & (STRIPE - 1);
        }
    }

    // ---- 3) two chunk phases: write transposed tile, FMA
    float acc[8] = {};
    #pragma unroll
    for (int p = 0; p < 4; p++)
        #pragma unroll
        for (int u = 0; u < 4; u++)
            tile[gq * 4 + u][p * 8 + rb] = ((const float*)&q[p])[u];
    __syncthreads();
    #pragma unroll
    for (int e = 0; e < 8; e++)
        acc[e] += hv[e][0] * tile[gg[e]][l32];
    __syncthreads();
    #pragma unroll
    for (int p = 0; p < 4; p++)
        #pragma unroll
        for (int u = 0; u < 4; u++)
            tile[gq * 4 + u][p * 8 + rb] = ((const float*)&q[4 + p])[u];
    __syncthreads();
    #pragma unroll
    for (int e = 0; e < 8; e++)
        acc[e] += hv[e][1] * tile[gg[e]][l32];

    // ---- 4) reduce in 32-lane half; masked write
    #pragma unroll
    for (int e = 0; e < 8; e++) {
        float sum = acc[e];
        sum += __shfl_xor(sum, 16, 64);
        sum += __shfl_xor(sum,  8, 64);
        sum += __shfl_xor(sum,  4, 64);
        sum += __shfl_xor(sum,  2, 64);
        sum += __shfl_xor(sum,  1, 64);
        int li = e * 8 + w * 2 + hw;
        if (li < cnt && l32 == 0)
            partial[(size_t)sl * NNZ + jj[e]] = sum;
    }

    // ---- 5) rare second pass (cnt > 64): re-stage (W3 chunk is L2-hot)
    for (int base = 64; base < cnt; base += 64) {
        int jj2[8], gg2[8];
        float hv2[8][2];
        #pragma unroll
        for (int e = 0; e < 8; e++) {
            int li = base + e * 8 + w * 2 + hw;
            if (li < cnt) {
                int4 Le = lists4[sb * CAP + li];
                jj2[e] = Le.x;
                const unsigned short* hp = H2b + ((size_t)s * N_CELLS + Le.y) * HDIM + k0;
                hv2[e][0] = b2f(hp[l32]);
                hv2[e][1] = b2f(hp[32 + l32]);
                gg2[e] = Le.z & (STRIPE - 1);
            } else { jj2[e] = -1; hv2[e][0] = hv2[e][1] = 0.f; gg2[e] = 0; }
        }
        float a2[8] = {};
        #pragma unroll
        for (int c = 0; c < 2; c++) {
            __syncthreads();
            #pragma unroll
            for (int p = 0; p < 4; p++) {
                float4 v = *(const float4*)(
                    Ws + (size_t)(k0 + c * 32 + p * 8 + rb) * N_GENES + gcl);
                #pragma unroll
                for (int u = 0; u < 4; u++)
                    tile[gq * 4 + u][p * 8 + rb] = ((const float*)&v)[u];
            }
            __syncthreads();
            #pragma unroll
            for (int e = 0; e < 8; e++)
                a2[e] += hv2[e][c] * tile[gg2[e]][l32];
        }
        #pragma unroll
        for (int e = 0; e < 8; e++) {
            float sum = a2[e];
            sum += __shfl_xor(sum, 16, 64);
            sum += __shfl_xor(sum,  8, 64);
            sum += __shfl_xor(sum,  4, 64);
            sum += __shfl_xor(sum,  2, 64);
            sum += __shfl_xor(sum,  1, 64);
            if (jj2[e] >= 0 && l32 == 0)
                partial[(size_t)sl * NNZ + jj2[e]] = sum;
        }
    }

    // ---- 6) overflow fallback on sl==0: writes ALL 16 slices for its entries
    if (sl == 0) {
        int novf = counts[NBUCKET];
        for (int i = sb * 4 + w; i < novf; i += NBUCKET * 4) {
            int j = ovf_list[i];
            int es = j >> 12;
            int bi = bidx[j], gi = gidx[j];
            const unsigned short* h = H2b + ((size_t)es * N_CELLS + bi) * HDIM;
            const float* wcol = W3 + (size_t)es * HDIM * N_GENES + gi;
            float sum = 0.f;
            #pragma unroll
            for (int t = 0; t < HDIM / 64; t++) {
                int k = t * 64 + lane;
                sum += b2f(h[k]) * wcol[(size_t)k * N_GENES];
            }
            #pragma unroll
            for (int off = 32; off; off >>= 1)
                sum += __shfl_xor(sum, off, 64);
            if (lane == 0) {
                partial[j] = sum;
                #pragma unroll
                for (int z2 = 1; z2 < NSLICE; z2++)
                    partial[(size_t)z2 * NNZ + j] = 0.f;
            }
        }
    }
}

// ---------------------------------------------------------------------------
// Kernel 5: finalize
// ---------------------------------------------------------------------------
__global__ __launch_bounds__(256) void finalize_out(
    const float* __restrict__ partial, const int* __restrict__ gidx,
    const float* __restrict__ b3, float* __restrict__ out)
{
    int j = blockIdx.x * 256 + threadIdx.x;
    int s = j >> 12;
    float x = b3[(size_t)s * N_GENES + gidx[j]];
    #pragma unroll
    for (int sl = 0; sl < NSLICE; sl++)
        x += partial[(size_t)sl * NNZ + j];
    out[j] = softplusf(x);
}

// ---------------------------------------------------------------------------
extern "C" void kernel_launch(void* const* d_in, const int* in_sizes, int n_in,
                              void* d_out, int out_size, void* d_ws, size_t ws_size,
                              hipStream_t stream) {
    const int*   batch_idx = (const int*)  d_in[1];
    const int*   gene_idx  = (const int*)  d_in[2];
    const float* gl        = (const float*)d_in[3];
    const float* z         = (const float*)d_in[4];
    const float* W1        = (const float*)d_in[5];
    const float* b1        = (const float*)d_in[6];
    const float* W2        = (const float*)d_in[7];
    const float* b2        = (const float*)d_in[8];
    const float* W3        = (const float*)d_in[9];
    const float* b3        = (const float*)d_in[10];
    float* out = (float*)d_out;

    char* ws = (char*)d_ws;
    unsigned short* Wt1   = (unsigned short*)(ws + 0);                //  4 MB (4,1024,512)
    unsigned short* Wt2   = (unsigned short*)(ws + (4ull  << 20));    //  8 MB (4,1024,1024)
    unsigned short* H1    = (unsigned short*)(ws + (12ull << 20));    //  4 MB (4,512,1024) bf16
    unsigned short* H2b   = (unsigned short*)(ws + (16ull << 20));    //  4 MB (4,512,1024) bf16
    int*            counts   = (int*)       (ws + (20ull << 20));     // 629 ints
    int4*           lists4   = (int4*)      (ws + (21ull << 20));     // 628*128 int4 (1.3 MB)
    int*            ovf_list = (int*)       (ws + (23ull << 20));     // NNZ ints
    float*          partial  = (float*)     (ws + (24ull << 20));     // 16*NNZ f32 (1 MB)

    // 1) weight transposes + fused single-block bucketing (was 3 launches)
    transpose_and_bucket<<<dim3(HDIM / 32, 49, N_SPECIES), dim3(32, 8), 0, stream>>>(
        W1, W2, Wt1, Wt2, batch_idx, gene_idx, counts, lists4, ovf_list);

    // 2) layer 1 with fused input build
    gemm1_fused<<<dim3(N_CELLS / 64, HDIM / 64, N_SPECIES), 256, 0, stream>>>(
        z, gl, batch_idx, Wt1, b1, H1);

    // 3) layer 2
    gemm_bf16_mfma<<<dim3(N_CELLS / 64, HDIM / 64, N_SPECIES), 256, 0, stream>>>(
        H1, Wt2, b2, H2b, N_CELLS, HDIM, HDIM);

    // 4) latency-ordered k-sliced decode
    decode_slice<<<dim3(NBUCKET, NSLICE), 256, 0, stream>>>(
        H2b, batch_idx, gene_idx, W3, counts, lists4, ovf_list, partial);

    // 5) finalize
    finalize_out<<<NNZ / 256, 256, 0, stream>>>(partial, gene_idx, b3, out);
}

// Round 14
// 114.942 us; speedup vs baseline: 1.3038x; 1.3038x over previous
//
#include <hip/hip_runtime.h>
#include <hip/hip_bf16.h>
#include <math.h>

#define N_SPECIES 4
#define NNZ       16384
#define MPS       4096      // NNZ / N_SPECIES
#define N_CELLS   512
#define N_LATENT  256
#define HDIM      1024
#define N_GENES   20000

#define STRIPE    128                       // genes per bucket stripe
#define NSTRIPE   157                       // ceil(20000/128)
#define NBUCKET   (N_SPECIES * NSTRIPE)     // 628
#define CAP       128
#define KCHUNK    32                        // k-rows per staged chunk
#define KSLICE    64                        // k-rows per decode block
#define NSLICE    (HDIM / KSLICE)           // 16

typedef __bf16 bf16x8 __attribute__((ext_vector_type(8)));
typedef float  f32x4  __attribute__((ext_vector_type(4)));

static __device__ __forceinline__ unsigned short f2b(float f) {
    __hip_bfloat16 h = __float2bfloat16(f);
    return __builtin_bit_cast(unsigned short, h);
}
static __device__ __forceinline__ float b2f(unsigned short u) {
    return __builtin_bit_cast(float, (unsigned int)u << 16);
}
static __device__ __forceinline__ float softplusf(float x) {
    return (x > 20.f) ? x : log1pf(expf(x));
}

// ---------------------------------------------------------------------------
// Kernel 1: both weight transposes in ONE launch (R12 structure — proven.
// R11 lesson: fusing into GEMM K-loop costs +20us; R13 lesson: fusing the
// bucketing in as a single serial block costs +34us. Keep them separate.)
// ---------------------------------------------------------------------------
__global__ __launch_bounds__(256) void transpose_w12(
    const float* __restrict__ W1, const float* __restrict__ W2,
    unsigned short* __restrict__ Wt1, unsigned short* __restrict__ Wt2)
{
    __shared__ float tile[32][33];
    int s = blockIdx.z, y = blockIdx.y;
    const float* Ws; unsigned short* Wts; int K, k0;
    if (y < 16) { Ws = W1 + (size_t)s * 512 * HDIM;  Wts = Wt1 + (size_t)s * HDIM * 512;  K = 512;  k0 = y * 32; }
    else        { Ws = W2 + (size_t)s * HDIM * HDIM; Wts = Wt2 + (size_t)s * HDIM * HDIM; K = HDIM; k0 = (y - 16) * 32; }
    int n0 = blockIdx.x * 32;
    int tx = threadIdx.x, ty = threadIdx.y;   // block (32, 8)
    #pragma unroll
    for (int p = 0; p < 4; p++)
        tile[ty + 8 * p][tx] = Ws[(size_t)(k0 + ty + 8 * p) * HDIM + n0 + tx];
    __syncthreads();
    #pragma unroll
    for (int p = 0; p < 4; p++) {
        int r = ty + 8 * p;
        Wts[(size_t)(n0 + r) * K + k0 + tx] = f2b(tile[tx][r]);
    }
}

// ---------------------------------------------------------------------------
// Kernel 2: GEMM layer 1 with FUSED input build (Wt1 bf16).
// ---------------------------------------------------------------------------
__global__ __launch_bounds__(256) void gemm1_fused(
    const float* __restrict__ z, const float* __restrict__ gl,
    const int* __restrict__ bidx, const unsigned short* __restrict__ Bt,
    const float* __restrict__ bias, unsigned short* __restrict__ C)
{
    int s = blockIdx.z;
    const unsigned short* Bs = Bt + (size_t)s * HDIM * 512;
    const float* bvec = bias + (size_t)s * HDIM;
    int m0 = blockIdx.x * 64, n0 = blockIdx.y * 64;

    __shared__ unsigned short Alds[64 * 64];
    __shared__ unsigned short Blds[64 * 64];

    int tid = threadIdx.x, lane = tid & 63, w = tid >> 6;
    int wr = w >> 1, wc = w & 1;
    f32x4 acc[2][2] = {};

    for (int kt = 0; kt < 512; kt += 64) {
        #pragma unroll
        for (int it = 0; it < 2; it++) {
            int c = it * 256 + tid;
            int row = c >> 3, kb = c & 7;
            int pa = kb ^ (row & 7);
            int col = kt + kb * 8;
            const float* src;
            if (col < N_LATENT)
                src = z + ((size_t)s * MPS + m0 + row) * N_LATENT + col;
            else
                src = gl + (size_t)bidx[s * MPS + m0 + row] * N_LATENT + (col - N_LATENT);
            float4 f0 = *(const float4*)src;
            float4 f1 = *(const float4*)(src + 4);
            unsigned short o[8] = { f2b(f0.x), f2b(f0.y), f2b(f0.z), f2b(f0.w),
                                    f2b(f1.x), f2b(f1.y), f2b(f1.z), f2b(f1.w) };
            *(uint4*)(Alds + row * 64 + pa * 8) = *(const uint4*)o;
            uint4 vb = *(const uint4*)(Bs + (size_t)(n0 + row) * 512 + kt + kb * 8);
            *(uint4*)(Blds + row * 64 + pa * 8) = vb;
        }
        __syncthreads();
        #pragma unroll
        for (int ks = 0; ks < 2; ks++) {
            bf16x8 af[2], bfr[2];
            #pragma unroll
            for (int f = 0; f < 2; f++) {
                int ar  = wr * 32 + f * 16 + (lane & 15);
                int akb = (ks * 4 + (lane >> 4)) ^ (ar & 7);
                af[f]  = __builtin_bit_cast(bf16x8, *(const uint4*)(Alds + ar * 64 + akb * 8));
                int br  = wc * 32 + f * 16 + (lane & 15);
                int bkb = (ks * 4 + (lane >> 4)) ^ (br & 7);
                bfr[f] = __builtin_bit_cast(bf16x8, *(const uint4*)(Blds + br * 64 + bkb * 8));
            }
            #pragma unroll
            for (int fm = 0; fm < 2; fm++)
                #pragma unroll
                for (int fn = 0; fn < 2; fn++)
                    acc[fm][fn] = __builtin_amdgcn_mfma_f32_16x16x32_bf16(
                        af[fm], bfr[fn], acc[fm][fn], 0, 0, 0);
        }
        __syncthreads();
    }

    #pragma unroll
    for (int fm = 0; fm < 2; fm++)
        #pragma unroll
        for (int fn = 0; fn < 2; fn++) {
            int col = n0 + wc * 32 + fn * 16 + (lane & 15);
            float bv = bvec[col];
            #pragma unroll
            for (int r = 0; r < 4; r++) {
                int row = m0 + wr * 32 + fm * 16 + (lane >> 4) * 4 + r;
                float v = fmaxf(acc[fm][fn][r] + bv, 0.0f);
                C[(size_t)s * N_CELLS * HDIM + (size_t)row * HDIM + col] = f2b(v);
            }
        }
}

// ---------------------------------------------------------------------------
// Kernel 3: generic bf16 MFMA GEMM (layer 2, Wt2 bf16)
// ---------------------------------------------------------------------------
__global__ __launch_bounds__(256) void gemm_bf16_mfma(
    const unsigned short* __restrict__ A, const unsigned short* __restrict__ Bt,
    const float* __restrict__ bias, unsigned short* __restrict__ C,
    int M, int N, int K)
{
    int s = blockIdx.z;
    const unsigned short* As = A  + (size_t)s * M * K;
    const unsigned short* Bs = Bt + (size_t)s * N * K;
    const float* bvec = bias + (size_t)s * N;
    int m0 = blockIdx.x * 64, n0 = blockIdx.y * 64;

    __shared__ unsigned short Alds[64 * 64];
    __shared__ unsigned short Blds[64 * 64];

    int tid = threadIdx.x, lane = tid & 63, w = tid >> 6;
    int wr = w >> 1, wc = w & 1;
    f32x4 acc[2][2] = {};

    for (int kt = 0; kt < K; kt += 64) {
        #pragma unroll
        for (int it = 0; it < 2; it++) {
            int c = it * 256 + tid;
            int row = c >> 3, kb = c & 7;
            int pa = kb ^ (row & 7);
            uint4 va = *(const uint4*)(As + (size_t)(m0 + row) * K + kt + kb * 8);
            *(uint4*)(Alds + row * 64 + pa * 8) = va;
            uint4 vb = *(const uint4*)(Bs + (size_t)(n0 + row) * K + kt + kb * 8);
            *(uint4*)(Blds + row * 64 + pa * 8) = vb;
        }
        __syncthreads();
        #pragma unroll
        for (int ks = 0; ks < 2; ks++) {
            bf16x8 af[2], bfr[2];
            #pragma unroll
            for (int f = 0; f < 2; f++) {
                int ar  = wr * 32 + f * 16 + (lane & 15);
                int akb = (ks * 4 + (lane >> 4)) ^ (ar & 7);
                af[f]  = __builtin_bit_cast(bf16x8, *(const uint4*)(Alds + ar * 64 + akb * 8));
                int br  = wc * 32 + f * 16 + (lane & 15);
                int bkb = (ks * 4 + (lane >> 4)) ^ (br & 7);
                bfr[f] = __builtin_bit_cast(bf16x8, *(const uint4*)(Blds + br * 64 + bkb * 8));
            }
            #pragma unroll
            for (int fm = 0; fm < 2; fm++)
                #pragma unroll
                for (int fn = 0; fn < 2; fn++)
                    acc[fm][fn] = __builtin_amdgcn_mfma_f32_16x16x32_bf16(
                        af[fm], bfr[fn], acc[fm][fn], 0, 0, 0);
        }
        __syncthreads();
    }

    #pragma unroll
    for (int fm = 0; fm < 2; fm++)
        #pragma unroll
        for (int fn = 0; fn < 2; fn++) {
            int col = n0 + wc * 32 + fn * 16 + (lane & 15);
            float bv = bvec[col];
            #pragma unroll
            for (int r = 0; r < 4; r++) {
                int row = m0 + wr * 32 + fm * 16 + (lane >> 4) * 4 + r;
                float v = fmaxf(acc[fm][fn][r] + bv, 0.0f);
                C[(size_t)s * M * N + (size_t)row * N + col] = f2b(v);
            }
        }
}

// ---------------------------------------------------------------------------
// Kernel 4a: zero bucket counters only (2.5 KB)
// ---------------------------------------------------------------------------
__global__ __launch_bounds__(256) void zero_counts(int* __restrict__ counts)
{
    int i = blockIdx.x * 256 + threadIdx.x;
    if (i <= NBUCKET) counts[i] = 0;
}

// ---------------------------------------------------------------------------
// Kernel 4b: bucket entries; pack (j, bi, gi)
// ---------------------------------------------------------------------------
__global__ __launch_bounds__(256) void bucket_pack(
    const int* __restrict__ bidx, const int* __restrict__ gidx,
    int* __restrict__ counts, int4* __restrict__ lists4, int* __restrict__ ovf_list)
{
    int j = blockIdx.x * 256 + threadIdx.x;
    int s = j >> 12;
    int g = gidx[j];
    int sb = s * NSTRIPE + (g >> 7);
    int pos = atomicAdd(&counts[sb], 1);
    if (pos < CAP) lists4[sb * CAP + pos] = make_int4(j, bidx[j], g, 0);
    else           ovf_list[atomicAdd(&counts[NBUCKET], 1)] = j;
}

// ---------------------------------------------------------------------------
// Kernel 5: k-sliced stripe decode, latency-ordered (R10/R12 structure).
// ---------------------------------------------------------------------------
__global__ __launch_bounds__(256) void decode_slice(
    const unsigned short* __restrict__ H2b, const int* __restrict__ bidx,
    const int* __restrict__ gidx, const float* __restrict__ W3,
    const int* __restrict__ counts, const int4* __restrict__ lists4,
    const int* __restrict__ ovf_list, float* __restrict__ partial)
{
    __shared__ float tile[STRIPE][KCHUNK + 1];   // [gene][k] transposed
    int sb = blockIdx.x, sl = blockIdx.y;
    int s  = sb / NSTRIPE;
    int g0 = (sb % NSTRIPE) * STRIPE;
    int tid = threadIdx.x, lane = tid & 63, w = tid >> 6;
    int hw = lane >> 5, l32 = lane & 31;
    int k0 = sl * KSLICE;
    const float* Ws = W3 + (size_t)s * HDIM * N_GENES;

    // ---- 1) ISSUE FIRST: 8x W3 float4 (both chunks)
    int rb = tid >> 5;                 // 0..7 (k-row sub-index)
    int gq = tid & 31;                 // gene quad within stripe
    int gcl = g0 + gq * 4;
    gcl = (gcl <= N_GENES - 4) ? gcl : (N_GENES - 4);   // tail clamp
    float4 q[8];
    #pragma unroll
    for (int c = 0; c < 2; c++)
        #pragma unroll
        for (int p = 0; p < 4; p++)
            q[c * 4 + p] = *(const float4*)(
                Ws + (size_t)(k0 + c * 32 + p * 8 + rb) * N_GENES + gcl);

    // ---- 2) metadata overlapped with W3 flight (speculative, clamped-safe)
    int cnt = counts[sb];
    int jj[8], gg[8];
    float hv[8][2];
    {
        int4 L[8];
        #pragma unroll
        for (int e = 0; e < 8; e++)
            L[e] = lists4[sb * CAP + (e * 8 + w * 2 + hw)];
        #pragma unroll
        for (int e = 0; e < 8; e++) {
            const unsigned short* hp =
                H2b + ((size_t)s * N_CELLS + (L[e].y & (N_CELLS - 1))) * HDIM + k0;
            hv[e][0] = b2f(hp[l32]);
            hv[e][1] = b2f(hp[32 + l32]);
            jj[e] = L[e].x;
            gg[e] = L[e].z & (STRIPE - 1);
        }
    }

    // ---- 3) two chunk phases: write transposed tile, FMA
    float acc[8] = {};
    #pragma unroll
    for (int p = 0; p < 4; p++)
        #pragma unroll
        for (int u = 0; u < 4; u++)
            tile[gq * 4 + u][p * 8 + rb] = ((const float*)&q[p])[u];
    __syncthreads();
    #pragma unroll
    for (int e = 0; e < 8; e++)
        acc[e] += hv[e][0] * tile[gg[e]][l32];
    __syncthreads();
    #pragma unroll
    for (int p = 0; p < 4; p++)
        #pragma unroll
        for (int u = 0; u < 4; u++)
            tile[gq * 4 + u][p * 8 + rb] = ((const float*)&q[4 + p])[u];
    __syncthreads();
    #pragma unroll
    for (int e = 0; e < 8; e++)
        acc[e] += hv[e][1] * tile[gg[e]][l32];

    // ---- 4) reduce in 32-lane half; masked write
    #pragma unroll
    for (int e = 0; e < 8; e++) {
        float sum = acc[e];
        sum += __shfl_xor(sum, 16, 64);
        sum += __shfl_xor(sum,  8, 64);
        sum += __shfl_xor(sum,  4, 64);
        sum += __shfl_xor(sum,  2, 64);
        sum += __shfl_xor(sum,  1, 64);
        int li = e * 8 + w * 2 + hw;
        if (li < cnt && l32 == 0)
            partial[(size_t)sl * NNZ + jj[e]] = sum;
    }

    // ---- 5) rare second pass (cnt > 64): re-stage (W3 chunk is L2-hot)
    for (int base = 64; base < cnt; base += 64) {
        int jj2[8], gg2[8];
        float hv2[8][2];
        #pragma unroll
        for (int e = 0; e < 8; e++) {
            int li = base + e * 8 + w * 2 + hw;
            if (li < cnt) {
                int4 Le = lists4[sb * CAP + li];
                jj2[e] = Le.x;
                const unsigned short* hp = H2b + ((size_t)s * N_CELLS + Le.y) * HDIM + k0;
                hv2[e][0] = b2f(hp[l32]);
                hv2[e][1] = b2f(hp[32 + l32]);
                gg2[e] = Le.z & (STRIPE - 1);
            } else { jj2[e] = -1; hv2[e][0] = hv2[e][1] = 0.f; gg2[e] = 0; }
        }
        float a2[8] = {};
        #pragma unroll
        for (int c = 0; c < 2; c++) {
            __syncthreads();
            #pragma unroll
            for (int p = 0; p < 4; p++) {
                float4 v = *(const float4*)(
                    Ws + (size_t)(k0 + c * 32 + p * 8 + rb) * N_GENES + gcl);
                #pragma unroll
                for (int u = 0; u < 4; u++)
                    tile[gq * 4 + u][p * 8 + rb] = ((const float*)&v)[u];
            }
            __syncthreads();
            #pragma unroll
            for (int e = 0; e < 8; e++)
                a2[e] += hv2[e][c] * tile[gg2[e]][l32];
        }
        #pragma unroll
        for (int e = 0; e < 8; e++) {
            float sum = a2[e];
            sum += __shfl_xor(sum, 16, 64);
            sum += __shfl_xor(sum,  8, 64);
            sum += __shfl_xor(sum,  4, 64);
            sum += __shfl_xor(sum,  2, 64);
            sum += __shfl_xor(sum,  1, 64);
            if (jj2[e] >= 0 && l32 == 0)
                partial[(size_t)sl * NNZ + jj2[e]] = sum;
        }
    }

    // ---- 6) overflow fallback on sl==0: writes ALL 16 slices for its entries
    if (sl == 0) {
        int novf = counts[NBUCKET];
        for (int i = sb * 4 + w; i < novf; i += NBUCKET * 4) {
            int j = ovf_list[i];
            int es = j >> 12;
            int bi = bidx[j], gi = gidx[j];
            const unsigned short* h = H2b + ((size_t)es * N_CELLS + bi) * HDIM;
            const float* wcol = W3 + (size_t)es * HDIM * N_GENES + gi;
            float sum = 0.f;
            #pragma unroll
            for (int t = 0; t < HDIM / 64; t++) {
                int k = t * 64 + lane;
                sum += b2f(h[k]) * wcol[(size_t)k * N_GENES];
            }
            #pragma unroll
            for (int off = 32; off; off >>= 1)
                sum += __shfl_xor(sum, off, 64);
            if (lane == 0) {
                partial[j] = sum;
                #pragma unroll
                for (int z2 = 1; z2 < NSLICE; z2++)
                    partial[(size_t)z2 * NNZ + j] = 0.f;
            }
        }
    }
}

// ---------------------------------------------------------------------------
// Kernel 6: finalize
// ---------------------------------------------------------------------------
__global__ __launch_bounds__(256) void finalize_out(
    const float* __restrict__ partial, const int* __restrict__ gidx,
    const float* __restrict__ b3, float* __restrict__ out)
{
    int j = blockIdx.x * 256 + threadIdx.x;
    int s = j >> 12;
    float x = b3[(size_t)s * N_GENES + gidx[j]];
    #pragma unroll
    for (int sl = 0; sl < NSLICE; sl++)
        x += partial[(size_t)sl * NNZ + j];
    out[j] = softplusf(x);
}

// ---------------------------------------------------------------------------
extern "C" void kernel_launch(void* const* d_in, const int* in_sizes, int n_in,
                              void* d_out, int out_size, void* d_ws, size_t ws_size,
                              hipStream_t stream) {
    const int*   batch_idx = (const int*)  d_in[1];
    const int*   gene_idx  = (const int*)  d_in[2];
    const float* gl        = (const float*)d_in[3];
    const float* z         = (const float*)d_in[4];
    const float* W1        = (const float*)d_in[5];
    const float* b1        = (const float*)d_in[6];
    const float* W2        = (const float*)d_in[7];
    const float* b2        = (const float*)d_in[8];
    const float* W3        = (const float*)d_in[9];
    const float* b3        = (const float*)d_in[10];
    float* out = (float*)d_out;

    char* ws = (char*)d_ws;
    unsigned short* Wt1   = (unsigned short*)(ws + 0);                //  4 MB (4,1024,512)
    unsigned short* Wt2   = (unsigned short*)(ws + (4ull  << 20));    //  8 MB (4,1024,1024)
    unsigned short* H1    = (unsigned short*)(ws + (12ull << 20));    //  4 MB (4,512,1024) bf16
    unsigned short* H2b   = (unsigned short*)(ws + (16ull << 20));    //  4 MB (4,512,1024) bf16
    int*            counts   = (int*)       (ws + (20ull << 20));     // 629 ints
    int4*           lists4   = (int4*)      (ws + (21ull << 20));     // 628*128 int4 (1.3 MB)
    int*            ovf_list = (int*)       (ws + (23ull << 20));     // NNZ ints
    float*          partial  = (float*)     (ws + (24ull << 20));     // 16*NNZ f32 (1 MB)

    // 1) zero counters (tiny); bucket entries
    zero_counts<<<(NBUCKET + 256) / 256, 256, 0, stream>>>(counts);
    bucket_pack<<<NNZ / 256, 256, 0, stream>>>(batch_idx, gene_idx, counts, lists4, ovf_list);

    // 2) both weight transposes, one launch
    transpose_w12<<<dim3(HDIM / 32, 48, N_SPECIES), dim3(32, 8), 0, stream>>>(W1, W2, Wt1, Wt2);

    // 3) layer 1 with fused input build
    gemm1_fused<<<dim3(N_CELLS / 64, HDIM / 64, N_SPECIES), 256, 0, stream>>>(
        z, gl, batch_idx, Wt1, b1, H1);

    // 4) layer 2
    gemm_bf16_mfma<<<dim3(N_CELLS / 64, HDIM / 64, N_SPECIES), 256, 0, stream>>>(
        H1, Wt2, b2, H2b, N_CELLS, HDIM, HDIM);

    // 5) latency-ordered k-sliced decode
    decode_slice<<<dim3(NBUCKET, NSLICE), 256, 0, stream>>>(
        H2b, batch_idx, gene_idx, W3, counts, lists4, ovf_list, partial);

    // 6) finalize
    finalize_out<<<NNZ / 256, 256, 0, stream>>>(partial, gene_idx, b3, out);
}